// Round 5
// baseline (6672.008 us; speedup 1.0000x reference)
//
#include <hip/hip_runtime.h>

// ---------------------------------------------------------------------------
// 2-layer ReLU RNN (B=64,T=512,I=256,H=512) + FC(512->1) + sigmoid. fp32 I/O.
// Scan: fp16 MFMA 16x16x32, W_hh fully register-resident (VGPR+AGPR unified
// file), ping-pong h in LDS, ONE raw barrier per step (lgkmcnt-only drain so
// global prefetch/stores stay in flight), xw software-pipelined 1 step ahead.
// ---------------------------------------------------------------------------

typedef _Float16 half8 __attribute__((ext_vector_type(8)));
typedef float    f32x4 __attribute__((ext_vector_type(4)));

#define T_DIM 512
#define H_DIM 512
#define B_DIM 64

__global__ __launch_bounds__(256) void conv_w_f16(
    const float* __restrict__ in, _Float16* __restrict__ out)
{
    int i = (blockIdx.x * 256 + threadIdx.x) * 4;
    float4 v = *(const float4*)(in + i);
    out[i + 0] = (_Float16)v.x;
    out[i + 1] = (_Float16)v.y;
    out[i + 2] = (_Float16)v.z;
    out[i + 3] = (_Float16)v.w;
}

// ---------------------------------------------------------------------------
// fp32 projection GEMM (unchanged): out[(t*64+b)][n] = A[b,t,:]·W[n,:] + b1+b2
// ---------------------------------------------------------------------------
__global__ __launch_bounds__(256) void gemm_proj_f32(
    const float* __restrict__ A,
    const float* __restrict__ W,
    const float* __restrict__ b1,
    const float* __restrict__ b2,
    float* __restrict__ out,
    int Kin)
{
    __shared__ float As[16][68];
    __shared__ float Bs[16][68];

    const int tx = threadIdx.x & 15;
    const int ty = threadIdx.x >> 4;
    const int r0 = blockIdx.x * 64;
    const int n0 = blockIdx.y * 64;

    float acc[4][4] = {};
    const int rr  = threadIdx.x >> 2;
    const int kk4 = (threadIdx.x & 3) * 4;

    for (int kc = 0; kc < Kin; kc += 16) {
        {
            int r = r0 + rr;
            int b = r & 63, t = r >> 6;
            float4 av = *(const float4*)(A + (size_t)(b * T_DIM + t) * Kin + kc + kk4);
            As[kk4 + 0][rr] = av.x; As[kk4 + 1][rr] = av.y;
            As[kk4 + 2][rr] = av.z; As[kk4 + 3][rr] = av.w;
            float4 wv = *(const float4*)(W + (size_t)(n0 + rr) * Kin + kc + kk4);
            Bs[kk4 + 0][rr] = wv.x; Bs[kk4 + 1][rr] = wv.y;
            Bs[kk4 + 2][rr] = wv.z; Bs[kk4 + 3][rr] = wv.w;
        }
        __syncthreads();
#pragma unroll
        for (int kk = 0; kk < 16; ++kk) {
            float4 av = *(const float4*)&As[kk][ty * 4];
            float4 bv = *(const float4*)&Bs[kk][tx * 4];
            float a[4] = {av.x, av.y, av.z, av.w};
            float b[4] = {bv.x, bv.y, bv.z, bv.w};
#pragma unroll
            for (int i = 0; i < 4; ++i)
#pragma unroll
                for (int j = 0; j < 4; ++j)
                    acc[i][j] = fmaf(a[i], b[j], acc[i][j]);
        }
        __syncthreads();
    }
#pragma unroll
    for (int j = 0; j < 4; ++j) {
        int n = n0 + tx * 4 + j;
        float bias = b1[n] + b2[n];
#pragma unroll
        for (int i = 0; i < 4; ++i) {
            int r = r0 + ty * 4 + i;
            out[(size_t)r * H_DIM + n] = acc[i][j] + bias;
        }
    }
}

// ---------------------------------------------------------------------------
// Persistent MFMA scan. grid=4 (16-batch groups), 512 thr (8 waves).
// Wave w owns n in [w*64, w*64+64). W16 ALL in registers (wreg[16][4], 256
// regs; RA spills MFMA B-operands to AGPRs — unified file).  h ping-pong in
// LDS; one lgkm-only barrier per step; xw prefetched one step ahead.
// ---------------------------------------------------------------------------
#define RAW_BARRIER() asm volatile("s_waitcnt lgkmcnt(0)\n\ts_barrier" ::: "memory")

template <int LAYER>
__global__ __launch_bounds__(512, 2) void rnn_scan_mfma(
    const float* __restrict__ xw,       // [T*B][H], row r = t*64+b, fp32
    const _Float16* __restrict__ W16,   // [512][512] fp16
    float* __restrict__ hout,           // L0: [B][T][H] fp32
    const float* __restrict__ wfc,      // L1: [512] fp32
    const float* __restrict__ bfc,      // L1: [1]
    float* __restrict__ outp)           // L1: [B][T] fp32
{
    __shared__ _Float16 hb[2][16][520];   // 2 x 16,640 B ping-pong

    const int tid  = threadIdx.x;
    const int w    = tid >> 6;
    const int lane = tid & 63;
    const int col  = lane & 15;
    const int q    = lane >> 4;
    const int g    = blockIdx.x;

    // zero both h buffers
    {
        _Float16* p = &hb[0][0][0];
        for (int i = tid; i < 2 * 16 * 520; i += 512) p[i] = (_Float16)0.f;
    }

    // W_hh fully register-resident: wreg[kt][nt]
    half8 wreg[16][4];
#pragma unroll
    for (int kt = 0; kt < 16; ++kt)
#pragma unroll
        for (int nt = 0; nt < 4; ++nt)
            wreg[kt][nt] = *(const half8*)(
                W16 + (size_t)(w * 64 + nt * 16 + col) * 512 + kt * 32 + q * 8);

    // FC weights (layer 1)
    const int fm  = tid >> 5;
    const int fcc = tid & 31;
    half8 wf0 = {}, wf1 = {};
    float bfcv = 0.f;
    if (LAYER == 1) {
#pragma unroll
        for (int j = 0; j < 8; ++j) {
            wf0[j] = (_Float16)wfc[fcc * 16 + j];
            wf1[j] = (_Float16)wfc[fcc * 16 + 8 + j];
        }
        bfcv = bfc[0];
    }

    __syncthreads();

    // xw prefetch registers (C/D owner positions)
    float xvA[16], xvB[16];
    {
        const float* xwt = xw + (size_t)(g * 16) * H_DIM;   // t = 0
#pragma unroll
        for (int nt = 0; nt < 4; ++nt)
#pragma unroll
            for (int r = 0; r < 4; ++r)
                xvA[nt * 4 + r] =
                    xwt[(size_t)(q * 4 + r) * H_DIM + w * 64 + nt * 16 + col];
    }

#define SCAN_STEP(SRC, DST, XV_CUR, XV_NXT, T_)                                   \
    {                                                                             \
        const int t_ = (T_);                                                      \
        /* prefetch xw for t+1 (clamped; stays in flight across raw barrier) */   \
        {                                                                         \
            int tn = t_ + 1; if (tn > 511) tn = 511;                              \
            const float* xwt = xw + ((size_t)tn * B_DIM + g * 16) * H_DIM;        \
            _Pragma("unroll")                                                     \
            for (int nt = 0; nt < 4; ++nt)                                        \
                _Pragma("unroll")                                                 \
                for (int r = 0; r < 4; ++r)                                       \
                    XV_NXT[nt * 4 + r] =                                          \
                        xwt[(size_t)(q * 4 + r) * H_DIM + w * 64 + nt * 16 + col];\
        }                                                                         \
        f32x4 acc[4] = {};                                                        \
        _Pragma("unroll")                                                         \
        for (int kt = 0; kt < 16; ++kt) {                                         \
            half8 a = *(const half8*)(&SRC[col][kt * 32 + q * 8]);                \
            _Pragma("unroll")                                                     \
            for (int nt = 0; nt < 4; ++nt)                                        \
                acc[nt] = __builtin_amdgcn_mfma_f32_16x16x32_f16(                 \
                    a, wreg[kt][nt], acc[nt], 0, 0, 0);                           \
        }                                                                         \
        _Pragma("unroll")                                                         \
        for (int nt = 0; nt < 4; ++nt)                                            \
            _Pragma("unroll")                                                     \
            for (int r = 0; r < 4; ++r) {                                         \
                float v = fmaxf(acc[nt][r] + XV_CUR[nt * 4 + r], 0.f);            \
                DST[q * 4 + r][w * 64 + nt * 16 + col] = (_Float16)v;             \
            }                                                                     \
        RAW_BARRIER();   /* lgkm-only drain: DST complete, VMEM stays queued */   \
        if (LAYER == 0) {                                                         \
            int m = tid >> 5, c = tid & 31;                                       \
            half8 v0 = *(const half8*)(&DST[m][c * 16]);                          \
            half8 v1 = *(const half8*)(&DST[m][c * 16 + 8]);                      \
            float* hp = hout + ((size_t)(g * 16 + m) * T_DIM + t_) * H_DIM + c * 16; \
            float4 o0 = {(float)v0[0], (float)v0[1], (float)v0[2], (float)v0[3]}; \
            float4 o1 = {(float)v0[4], (float)v0[5], (float)v0[6], (float)v0[7]}; \
            float4 o2 = {(float)v1[0], (float)v1[1], (float)v1[2], (float)v1[3]}; \
            float4 o3 = {(float)v1[4], (float)v1[5], (float)v1[6], (float)v1[7]}; \
            *(float4*)(hp + 0)  = o0;                                             \
            *(float4*)(hp + 4)  = o1;                                             \
            *(float4*)(hp + 8)  = o2;                                             \
            *(float4*)(hp + 12) = o3;                                             \
        } else {                                                                  \
            half8 v0 = *(const half8*)(&DST[fm][fcc * 16]);                       \
            half8 v1 = *(const half8*)(&DST[fm][fcc * 16 + 8]);                   \
            float p = 0.f;                                                        \
            _Pragma("unroll")                                                     \
            for (int j = 0; j < 8; ++j)                                           \
                p += (float)v0[j] * (float)wf0[j] + (float)v1[j] * (float)wf1[j]; \
            _Pragma("unroll")                                                     \
            for (int s = 1; s < 32; s <<= 1) p += __shfl_xor(p, s);               \
            if (fcc == 0) {                                                       \
                float lg = p + bfcv;                                              \
                outp[(size_t)(g * 16 + fm) * T_DIM + t_] = 1.f / (1.f + __expf(-lg)); \
            }                                                                     \
        }                                                                         \
    }

    for (int t = 0; t < T_DIM; t += 2) {
        SCAN_STEP(hb[0], hb[1], xvA, xvB, t);
        SCAN_STEP(hb[1], hb[0], xvB, xvA, t + 1);
    }
#undef SCAN_STEP
}

// ---------------------------------------------------------------------------
extern "C" void kernel_launch(void* const* d_in, const int* in_sizes, int n_in,
                              void* d_out, int out_size, void* d_ws, size_t ws_size,
                              hipStream_t stream)
{
    const float* x     = (const float*)d_in[0];
    const float* W_ih0 = (const float*)d_in[1];
    const float* W_hh0 = (const float*)d_in[2];
    const float* b_ih0 = (const float*)d_in[3];
    const float* b_hh0 = (const float*)d_in[4];
    const float* W_ih1 = (const float*)d_in[5];
    const float* W_hh1 = (const float*)d_in[6];
    const float* b_ih1 = (const float*)d_in[7];
    const float* b_hh1 = (const float*)d_in[8];
    const float* W_fc  = (const float*)d_in[9];
    const float* b_fc  = (const float*)d_in[10];

    float* ws = (float*)d_ws;
    float* xw = ws;                                       // 67.1 MB [T*B][H]
    float* h0 = xw + (size_t)T_DIM * B_DIM * H_DIM;       // 67.1 MB [B][T][H]
    _Float16* W16_0 = (_Float16*)(h0 + (size_t)T_DIM * B_DIM * H_DIM);  // 512 KB
    _Float16* W16_1 = W16_0 + (size_t)H_DIM * H_DIM;                    // 512 KB

    conv_w_f16<<<256, 256, 0, stream>>>(W_hh0, W16_0);
    conv_w_f16<<<256, 256, 0, stream>>>(W_hh1, W16_1);

    dim3 gp((T_DIM * B_DIM) / 64, H_DIM / 64);

    gemm_proj_f32<<<gp, 256, 0, stream>>>(x, W_ih0, b_ih0, b_hh0, xw, 256);
    rnn_scan_mfma<0><<<4, 512, 0, stream>>>(xw, W16_0, h0, nullptr, nullptr, nullptr);

    gemm_proj_f32<<<gp, 256, 0, stream>>>(h0, W_ih1, b_ih1, b_hh1, xw, 512);
    rnn_scan_mfma<1><<<4, 512, 0, stream>>>(xw, W16_1, nullptr, W_fc, b_fc,
                                            (float*)d_out);
}

// Round 6
// 2880.430 us; speedup vs baseline: 2.3163x; 2.3163x over previous
//
#include <hip/hip_runtime.h>

// ---------------------------------------------------------------------------
// 2-layer ReLU RNN (B=64,T=512,I=256,H=512) + FC(512->1) + sigmoid. fp32 I/O.
// Scan: fp16 MFMA 16x16x32. W_hh: 12 k-tiles in regs + 4 k-tiles in LDS
// (B-frag lane-sequential, conflict-free). h state in LDS A-frag lane-seq
// layout (conflict-free reads). Raw lgkm-only barriers. xw fp16 frag-packed;
// h0 fp16 A-seq layout consumed directly by the layer-1 projection.
// ---------------------------------------------------------------------------

typedef _Float16 half8 __attribute__((ext_vector_type(8)));
typedef _Float16 half4 __attribute__((ext_vector_type(4)));
typedef float    f32x4 __attribute__((ext_vector_type(4)));

#define T_DIM 512
#define H_DIM 512
#define B_DIM 64

#define RAW_BARRIER() asm volatile("s_waitcnt lgkmcnt(0)\n\ts_barrier" ::: "memory")

__global__ __launch_bounds__(256) void conv_w_f16(
    const float* __restrict__ in, _Float16* __restrict__ out)
{
    int i = (blockIdx.x * 256 + threadIdx.x) * 4;
    float4 v = *(const float4*)(in + i);
    out[i + 0] = (_Float16)v.x;
    out[i + 1] = (_Float16)v.y;
    out[i + 2] = (_Float16)v.z;
    out[i + 3] = (_Float16)v.w;
}

// ---------------------------------------------------------------------------
// Projection GEMM. AMODE 0: A fp32 plain [B][T][Kin].
//                  AMODE 1: A fp16 A-seq layout [g][t][kt][qa*16+m][8].
// Output xw fp16, C-frag-packed per (t,g): idx = (n>>4)*256 + (m>>2)*64
//                                               + (n&15)*4 + (m&3).
// grid (T, 8), block 256. Block covers t = blockIdx.x, all 64 b, 64 n.
// ---------------------------------------------------------------------------
template <int AMODE>
__global__ __launch_bounds__(256) void gemm_proj(
    const float* __restrict__ A32,
    const _Float16* __restrict__ A16,
    const float* __restrict__ W,
    const float* __restrict__ b1,
    const float* __restrict__ b2,
    _Float16* __restrict__ xwF,
    int Kin)
{
    __shared__ float As[16][68];
    __shared__ float Bs[16][68];

    const int tx = threadIdx.x & 15;
    const int ty = threadIdx.x >> 4;
    const int t  = blockIdx.x;
    const int n0 = blockIdx.y * 64;

    float acc[4][4] = {};
    const int rr  = threadIdx.x >> 2;        // 0..63 = batch b
    const int kk4 = (threadIdx.x & 3) * 4;

    for (int kc = 0; kc < Kin; kc += 16) {
        if (AMODE == 0) {
            float4 av = *(const float4*)(A32 + (size_t)(rr * T_DIM + t) * Kin + kc + kk4);
            As[kk4 + 0][rr] = av.x; As[kk4 + 1][rr] = av.y;
            As[kk4 + 2][rr] = av.z; As[kk4 + 3][rr] = av.w;
        } else {
            int g = rr >> 4, m = rr & 15;
            int k = kc + kk4;
            int kt = k >> 5, qa = (k >> 3) & 3, jj = k & 7;
            half4 av = *(const half4*)(
                A16 + ((size_t)(g * T_DIM + t) * 16 + kt) * 512 + (qa * 16 + m) * 8 + jj);
            As[kk4 + 0][rr] = (float)av[0]; As[kk4 + 1][rr] = (float)av[1];
            As[kk4 + 2][rr] = (float)av[2]; As[kk4 + 3][rr] = (float)av[3];
        }
        {
            float4 wv = *(const float4*)(W + (size_t)(n0 + rr) * Kin + kc + kk4);
            Bs[kk4 + 0][rr] = wv.x; Bs[kk4 + 1][rr] = wv.y;
            Bs[kk4 + 2][rr] = wv.z; Bs[kk4 + 3][rr] = wv.w;
        }
        __syncthreads();
#pragma unroll
        for (int kk = 0; kk < 16; ++kk) {
            float4 av = *(const float4*)&As[kk][ty * 4];
            float4 bv = *(const float4*)&Bs[kk][tx * 4];
            float a[4] = {av.x, av.y, av.z, av.w};
            float b[4] = {bv.x, bv.y, bv.z, bv.w};
#pragma unroll
            for (int i = 0; i < 4; ++i)
#pragma unroll
                for (int j = 0; j < 4; ++j)
                    acc[i][j] = fmaf(a[i], b[j], acc[i][j]);
        }
        __syncthreads();
    }

    // epilogue: rows b = ty*4+i (g = ty>>2, m = (ty&3)*4+i), cols n = n0+tx*4+j
    // frag-packed store: pack half4 over i (m&3 = i is the fastest axis).
#pragma unroll
    for (int j = 0; j < 4; ++j) {
        int n = n0 + tx * 4 + j;
        float bias = b1[n] + b2[n];
        half4 hv;
#pragma unroll
        for (int i = 0; i < 4; ++i) hv[i] = (_Float16)(acc[i][j] + bias);
        size_t addr = ((size_t)t * 4 + (ty >> 2)) * 8192
                    + ((size_t)blockIdx.y * 4 + (tx >> 2)) * 256
                    + (ty & 3) * 64 + ((tx & 3) * 4 + j) * 4;
        *(half4*)&xwF[addr] = hv;
    }
}

// ---------------------------------------------------------------------------
// Persistent MFMA scan. grid=4, 512 thr (8 waves). Wave w owns n in
// [w*64, w*64+64). wreg: k-tiles 0..11 (192 regs). WlB (LDS, 128 KB):
// k-tiles 12..15, B-frag lane-seq: [(kt*8+... actually (kt*32 + w*4 + nt)][lane].
// hA (LDS, 16 KB): A-frag lane-seq [kt][qa*16+m][8].
// ---------------------------------------------------------------------------
template <int LAYER>
__global__ __launch_bounds__(512, 2) void rnn_scan_mfma(
    const _Float16* __restrict__ xwF,   // frag-packed [t][g][8192]
    const _Float16* __restrict__ W16,   // [512][512] fp16
    _Float16* __restrict__ h0A,         // L0 out: A-seq [g][t][kt][lane][8]
    const float* __restrict__ wfc,      // L1: [512]
    const float* __restrict__ bfc,      // L1: [1]
    float* __restrict__ outp)           // L1: [B][T]
{
    __shared__ _Float16 WlB[65536];     // 128 KB
    __shared__ _Float16 hA[8192];       // 16 KB

    const int tid  = threadIdx.x;
    const int w    = tid >> 6;
    const int lane = tid & 63;
    const int col  = lane & 15;
    const int q    = lane >> 4;
    const int g    = blockIdx.x;

    // zero h
    {
        half8 z = {};
        *(half8*)&hA[tid * 8]        = z;
        *(half8*)&hA[(tid + 512) * 8] = z;
    }
    // WlB init: B-frag lane-sequential, k-tiles 12..15
#pragma unroll
    for (int kt = 0; kt < 4; ++kt)
#pragma unroll
        for (int nt = 0; nt < 4; ++nt)
            *(half8*)&WlB[((kt * 32 + w * 4 + nt) * 512) + lane * 8] =
                *(const half8*)(W16 + (size_t)(w * 64 + nt * 16 + col) * 512
                                + (12 + kt) * 32 + q * 8);
    // wreg: k-tiles 0..11
    half8 wreg[12][4];
#pragma unroll
    for (int kt = 0; kt < 12; ++kt)
#pragma unroll
        for (int nt = 0; nt < 4; ++nt)
            wreg[kt][nt] = *(const half8*)(
                W16 + (size_t)(w * 64 + nt * 16 + col) * 512 + kt * 32 + q * 8);

    // FC weights (layer 1)
    const int fm  = tid >> 5;
    const int fcc = tid & 31;
    half8 wf0 = {}, wf1 = {};
    float bfcv = 0.f;
    if (LAYER == 1) {
#pragma unroll
        for (int j = 0; j < 8; ++j) {
            wf0[j] = (_Float16)wfc[fcc * 16 + j];
            wf1[j] = (_Float16)wfc[fcc * 16 + 8 + j];
        }
        bfcv = bfc[0];
    }

    __syncthreads();

    // xw prefetch (frag-packed: one half4 per nt)
    half4 xvA[4], xvB[4];
#pragma unroll
    for (int nt = 0; nt < 4; ++nt)
        xvA[nt] = *(const half4*)(
            xwF + (size_t)g * 8192 + (w * 4 + nt) * 256 + q * 64 + col * 4);

#define SCAN_STEP(XV_CUR, XV_NXT, T_)                                             \
    {                                                                             \
        const int t_ = (T_);                                                      \
        {                                                                         \
            int tn = t_ + 1; if (tn > 511) tn = 511;                              \
            const _Float16* xwp = xwF + ((size_t)tn * 4 + g) * 8192;              \
            _Pragma("unroll")                                                     \
            for (int nt = 0; nt < 4; ++nt)                                        \
                XV_NXT[nt] = *(const half4*)(xwp + (w * 4 + nt) * 256             \
                                             + q * 64 + col * 4);                 \
        }                                                                         \
        f32x4 acc[4] = {};                                                        \
        _Pragma("unroll")                                                         \
        for (int kt = 0; kt < 16; ++kt) {                                         \
            half8 a = *(const half8*)&hA[(kt * 64 + lane) * 8];                   \
            _Pragma("unroll")                                                     \
            for (int nt = 0; nt < 4; ++nt) {                                      \
                half8 b;                                                          \
                if (kt < 12) b = wreg[kt][nt];                                    \
                else b = *(const half8*)&WlB[(((kt - 12) * 32 + w * 4 + nt) * 512)\
                                             + lane * 8];                         \
                acc[nt] = __builtin_amdgcn_mfma_f32_16x16x32_f16(                 \
                    a, b, acc[nt], 0, 0, 0);                                      \
            }                                                                     \
        }                                                                         \
        RAW_BARRIER();  /* all A-reads of h_{t-1} done; VMEM stays in flight */   \
        _Pragma("unroll")                                                         \
        for (int nt = 0; nt < 4; ++nt) {                                          \
            int nn = nt * 16 + col;                                               \
            int kt_a = 2 * w + (nn >> 5);                                         \
            int qa   = (nn >> 3) & 3;                                             \
            int jj   = nn & 7;                                                    \
            _Pragma("unroll")                                                     \
            for (int r = 0; r < 4; ++r) {                                         \
                float v = fmaxf(acc[nt][r] + (float)XV_CUR[nt][r], 0.f);          \
                hA[(kt_a * 64 + qa * 16 + q * 4 + r) * 8 + jj] = (_Float16)v;     \
            }                                                                     \
        }                                                                         \
        RAW_BARRIER();  /* h_t visible */                                         \
        if (LAYER == 0) {                                                         \
            _Pragma("unroll")                                                     \
            for (int e = 0; e < 2; ++e) {                                         \
                half8 v = *(const half8*)&hA[((w * 2 + e) * 64 + lane) * 8];      \
                *(half8*)(h0A + ((size_t)(g * T_DIM + t_) * 16 + w * 2 + e) * 512 \
                          + lane * 8) = v;                                        \
            }                                                                     \
        } else {                                                                  \
            half8 v0 = *(const half8*)&hA[((fcc >> 1) * 64                        \
                           + ((fcc & 1) * 2 + 0) * 16 + fm) * 8];                 \
            half8 v1 = *(const half8*)&hA[((fcc >> 1) * 64                        \
                           + ((fcc & 1) * 2 + 1) * 16 + fm) * 8];                 \
            float p = 0.f;                                                        \
            _Pragma("unroll")                                                     \
            for (int j = 0; j < 8; ++j)                                           \
                p += (float)v0[j] * (float)wf0[j] + (float)v1[j] * (float)wf1[j]; \
            _Pragma("unroll")                                                     \
            for (int s = 1; s < 32; s <<= 1) p += __shfl_xor(p, s);               \
            if (fcc == 0) {                                                       \
                float lg = p + bfcv;                                              \
                outp[(size_t)(g * 16 + fm) * T_DIM + t_] =                        \
                    1.f / (1.f + __expf(-lg));                                    \
            }                                                                     \
        }                                                                         \
    }

    for (int t = 0; t < T_DIM; t += 2) {
        SCAN_STEP(xvA, xvB, t);
        SCAN_STEP(xvB, xvA, t + 1);
    }
#undef SCAN_STEP
}

// ---------------------------------------------------------------------------
extern "C" void kernel_launch(void* const* d_in, const int* in_sizes, int n_in,
                              void* d_out, int out_size, void* d_ws, size_t ws_size,
                              hipStream_t stream)
{
    const float* x     = (const float*)d_in[0];
    const float* W_ih0 = (const float*)d_in[1];
    const float* W_hh0 = (const float*)d_in[2];
    const float* b_ih0 = (const float*)d_in[3];
    const float* b_hh0 = (const float*)d_in[4];
    const float* W_ih1 = (const float*)d_in[5];
    const float* W_hh1 = (const float*)d_in[6];
    const float* b_ih1 = (const float*)d_in[7];
    const float* b_hh1 = (const float*)d_in[8];
    const float* W_fc  = (const float*)d_in[9];
    const float* b_fc  = (const float*)d_in[10];

    _Float16* xwF  = (_Float16*)d_ws;                          // 33.5 MB
    _Float16* h0A  = xwF + (size_t)T_DIM * 4 * 8192;           // 33.5 MB
    _Float16* W16_0 = h0A + (size_t)4 * T_DIM * 16 * 512;      // 512 KB
    _Float16* W16_1 = W16_0 + (size_t)H_DIM * H_DIM;           // 512 KB

    conv_w_f16<<<256, 256, 0, stream>>>(W_hh0, W16_0);
    conv_w_f16<<<256, 256, 0, stream>>>(W_hh1, W16_1);

    dim3 gp(T_DIM, 8);

    gemm_proj<0><<<gp, 256, 0, stream>>>(x, nullptr, W_ih0, b_ih0, b_hh0, xwF, 256);
    rnn_scan_mfma<0><<<4, 512, 0, stream>>>(xwF, W16_0, h0A, nullptr, nullptr, nullptr);

    gemm_proj<1><<<gp, 256, 0, stream>>>(nullptr, h0A, W_ih1, b_ih1, b_hh1, xwF, 512);
    rnn_scan_mfma<1><<<4, 512, 0, stream>>>(xwF, W16_1, nullptr, W_fc, b_fc,
                                            (float*)d_out);
}